// Round 13
// baseline (928.300 us; speedup 1.0000x reference)
//
#include <hip/hip_runtime.h>

typedef __attribute__((ext_vector_type(8))) _Float16 f16x8;
typedef __attribute__((ext_vector_type(4))) float f32x4;

static constexpr int   B_  = 64;
static constexpr int   T_  = 256;
static constexpr int   D_  = 512;
static constexpr int   N_  = 1024;
static constexpr float ALPHA_ = 0.9f;
static constexpr float BETA_  = 0.85f;
static constexpr float THR_   = 0.1f;
static constexpr float INV4096 = 1.0f / 4096.0f;

// ========== Kernel 0: pre-split + pre-fragment W into MFMA B-blocks ==========
__global__ __launch_bounds__(256) void dsrnn_wsplit(const float* __restrict__ W,
                                                    unsigned char* __restrict__ Wfrag) {
  const int u    = blockIdx.x * 256 + threadIdx.x;   // 0..65535
  const int lane = u & 63;
  const int bi   = u >> 6;        // 0..1023 = cf*16 + ch
  const int cf   = bi >> 4;
  const int chk  = bi & 15;
  const int kg   = lane >> 4;
  const int cc   = lane & 15;
  const int n    = cf * 16 + cc;
  const int k0   = chk * 32 + kg * 8;
  f16x8 vh, vl;
#pragma unroll
  for (int j = 0; j < 8; ++j) {
    const float v = W[(size_t)(k0 + j) * N_ + n];
    const _Float16 h = (_Float16)v;
    vh[j] = h;
    vl[j] = (_Float16)((v - (float)h) * 4096.0f);
  }
  unsigned char* dst = Wfrag + (size_t)bi * 2048 + lane * 16;
  *reinterpret_cast<f16x8*>(dst)        = vh;
  *reinterpret_cast<f16x8*>(dst + 1024) = vl;
}

// ================= Kernel 1: H = X @ W via MFMA (fp16 3-product) =============
__global__ __launch_bounds__(256) void dsrnn_hgemm2(const float* __restrict__ X,
                                                    const unsigned char* __restrict__ Wfrag,
                                                    float* __restrict__ H) {
  __shared__ __align__(16) _Float16 Xa_hi[64][40];
  __shared__ __align__(16) _Float16 Xa_lo[64][40];
  const int tid  = threadIdx.x;
  const int rb   = blockIdx.x >> 3;
  const int nb   = (blockIdx.x & 7) << 7;
  const int r0   = rb << 6;
  const int wv   = tid >> 6;
  const int lane = tid & 63;
  const int kg   = lane >> 4;
  const int cc   = lane & 15;

  f32x4 ah[4][2], am[4][2];
#pragma unroll
  for (int i = 0; i < 4; ++i)
#pragma unroll
    for (int j = 0; j < 2; ++j) {
      ah[i][j] = (f32x4){0.f, 0.f, 0.f, 0.f};
      am[i][j] = (f32x4){0.f, 0.f, 0.f, 0.f};
    }

  const int srow = tid >> 2;
  const int skq  = (tid & 3) << 3;

  for (int kc = 0; kc < 16; ++kc) {
    {
      const float* xp = X + (size_t)(r0 + srow) * D_ + kc * 32 + skq;
      const float4 v0 = *reinterpret_cast<const float4*>(xp);
      const float4 v1 = *reinterpret_cast<const float4*>(xp + 4);
      const float vv[8] = {v0.x, v0.y, v0.z, v0.w, v1.x, v1.y, v1.z, v1.w};
      f16x8 xh, xl;
#pragma unroll
      for (int j = 0; j < 8; ++j) {
        const _Float16 h = (_Float16)vv[j];
        xh[j] = h;
        xl[j] = (_Float16)((vv[j] - (float)h) * 4096.0f);
      }
      *reinterpret_cast<f16x8*>(&Xa_hi[srow][skq]) = xh;
      *reinterpret_cast<f16x8*>(&Xa_lo[srow][skq]) = xl;
    }
    __syncthreads();

    f16x8 Bh[2], Bl[2];
#pragma unroll
    for (int cfi = 0; cfi < 2; ++cfi) {
      const unsigned char* bp =
          Wfrag + (size_t)((((nb >> 4) + (wv << 1) + cfi) * 16 + kc) * 2048) + lane * 16;
      Bh[cfi] = *reinterpret_cast<const f16x8*>(bp);
      Bl[cfi] = *reinterpret_cast<const f16x8*>(bp + 1024);
    }

#pragma unroll
    for (int rf = 0; rf < 4; ++rf) {
      const f16x8 Ah = *reinterpret_cast<const f16x8*>(&Xa_hi[rf * 16 + cc][kg * 8]);
      const f16x8 Al = *reinterpret_cast<const f16x8*>(&Xa_lo[rf * 16 + cc][kg * 8]);
#pragma unroll
      for (int cfi = 0; cfi < 2; ++cfi) {
        ah[rf][cfi] = __builtin_amdgcn_mfma_f32_16x16x32_f16(Ah, Bh[cfi], ah[rf][cfi], 0, 0, 0);
        am[rf][cfi] = __builtin_amdgcn_mfma_f32_16x16x32_f16(Ah, Bl[cfi], am[rf][cfi], 0, 0, 0);
        am[rf][cfi] = __builtin_amdgcn_mfma_f32_16x16x32_f16(Al, Bh[cfi], am[rf][cfi], 0, 0, 0);
      }
    }
    __syncthreads();
  }

#pragma unroll
  for (int rf = 0; rf < 4; ++rf)
#pragma unroll
    for (int cfi = 0; cfi < 2; ++cfi) {
      const int col = nb + wv * 32 + cfi * 16 + cc;
#pragma unroll
      for (int rr = 0; rr < 4; ++rr) {
        const int row = r0 + rf * 16 + kg * 4 + rr;
        H[(size_t)row * N_ + col] = fmaf(am[rf][cfi][rr], INV4096, ah[rf][cfi][rr]);
      }
    }
}

// ====== Kernel 2: persistent recurrence via MFMA (fp16 hi + scaled-lo) =======
// EXACT r9 structure (660 us step: whole-WG throttled parallel spin, LDS mask
// stage, 2 barriers, stores at loop end after publish) with ONE change:
// masks layout transposed [b][mg] -> [mg][b]. Old layout: a 64B MALL line held
// words (b, mg..mg+7) written by 8 DIFFERENT WGs/step -> write-shared line
// bounces serially in MALL on the publish->detect critical path. New layout:
// each WG's 16 publishes = 2 exclusively-owned contiguous lines; no line has
// more than one writer. Reads share lines harmlessly. Same tag protocol.
__global__ __launch_bounds__(256, 1) void dsrnn_step13(
    const float* __restrict__ Rw,
    float* __restrict__ spk_rec,
    float* __restrict__ mem_rec,
    float* __restrict__ syn_rec,   // pre-filled with H, overwritten with syn
    float* __restrict__ mem_fin,
    float* __restrict__ syn_fin,
    float* __restrict__ spk_fin,
    unsigned long long* masks)     // [2 parity][32 mg][64 b]
{
  extern __shared__ unsigned char RsB[];   // 128 KB fragment blocks
  __shared__ unsigned smaskU[16][33];      // padded
  __shared__ float scratch[4][512];        // per-wave C partials [wv][b*32+m]

  const int tid  = threadIdx.x;
  const int bq   = blockIdx.x >> 5;
  const int mg   = blockIdx.x & 31;
  const int wv   = tid >> 6;
  const int lane = tid & 63;
  const int kg   = lane >> 4;
  const int cc   = lane & 15;

  // ---- one-time preload: R[:, mg*32..+32) -> fp16 hi / scaled-lo blocks ----
  for (int k = 0; k < 128; ++k) {
    const int e  = (k << 8) + tid;
    const int n  = e >> 5;
    const int ml = e & 31;
    const float v = Rw[(size_t)n * N_ + (mg << 5) + ml];
    const _Float16 hi = (_Float16)v;
    const float hif = (float)hi;
    const _Float16 lo = (_Float16)((v - hif) * 4096.0f);
    const int s   = n >> 5;
    const int kin = n & 31;
    const int ln  = ((kin >> 3) << 4) + (ml & 15);
    const int mt  = ml >> 4;
    const int off = ((((s << 1) + mt) << 1) << 10) + (ln << 4) + ((kin & 7) << 1);
    *(_Float16*)(RsB + off)        = hi;
    *(_Float16*)(RsB + off + 1024) = lo;
  }

  const int bl1 = tid >> 5;                // 0..7
  const int bl2 = bl1 + 8;
  const int ml_ = tid & 31;
  const int b1  = (bq << 4) + bl1;
  const int b2  = (bq << 4) + bl2;
  const int m   = (mg << 5) + ml_;

  float mem1 = 0.f, syn1 = 0.f, spv1 = 0.f;
  float mem2 = 0.f, syn2 = 0.f, spv2 = 0.f;

  __syncthreads();                         // preload visible to all

  for (int t = 0; t < T_; ++t) {
    const size_t i1 = ((size_t)b1 * T_ + t) * N_ + m;
    const size_t i2 = ((size_t)b2 * T_ + t) * N_ + m;
    const float h1 = syn_rec[i1];          // issue early, consumed post-GEMM
    const float h2 = syn_rec[i2];

    // ---- PARALLEL throttled spin; word (b, chunk c) at index c*64 + b ----
    {
      unsigned long long* base = masks + (size_t)(t & 1) * 2048;
      unsigned long long* p1 = base + (size_t)ml_ * 64 + b1;
      unsigned long long* p2 = base + (size_t)ml_ * 64 + b2;
      unsigned long long w1 =
          __hip_atomic_load(p1, __ATOMIC_RELAXED, __HIP_MEMORY_SCOPE_AGENT);
      unsigned long long w2 =
          __hip_atomic_load(p2, __ATOMIC_RELAXED, __HIP_MEMORY_SCOPE_AGENT);
      int g = 0;
      while ((((unsigned)(w1 >> 32) != (unsigned)t) |
              ((unsigned)(w2 >> 32) != (unsigned)t)) && ++g < (1 << 20)) {
        __builtin_amdgcn_s_sleep(1);
        w1 = __hip_atomic_load(p1, __ATOMIC_RELAXED, __HIP_MEMORY_SCOPE_AGENT);
        w2 = __hip_atomic_load(p2, __ATOMIC_RELAXED, __HIP_MEMORY_SCOPE_AGENT);
      }
      smaskU[bl1][ml_] = (unsigned)w1;
      smaskU[bl2][ml_] = (unsigned)w2;
    }
    __syncthreads();                       // #1: masks staged

    // ---- MFMA phase: wave's 8 K-steps; hi and lo into separate fp32 C ----
    f32x4 c0h = {0.f, 0.f, 0.f, 0.f};
    f32x4 c0l = {0.f, 0.f, 0.f, 0.f};
    f32x4 c1h = {0.f, 0.f, 0.f, 0.f};
    f32x4 c1l = {0.f, 0.f, 0.f, 0.f};
    const int shB = kg << 3;
#pragma unroll
    for (int ss = 0; ss < 8; ++ss) {
      const int s = (wv << 3) + ss;
      const unsigned bits8 = (smaskU[cc][s] >> shB) & 0xFFu;
      union { unsigned u[4]; f16x8 v; } A;
#pragma unroll
      for (int p = 0; p < 4; ++p) {
        const unsigned e0 = (bits8 >> (2 * p)) & 1u;
        const unsigned e1 = (bits8 >> (2 * p + 1)) & 1u;
        A.u[p] = e0 * 0x3C00u + e1 * 0x3C000000u;   // fp16 1.0 per slot
      }
      const unsigned char* sb = RsB + (s << 12) + (lane << 4);
      const f16x8 b00 = *reinterpret_cast<const f16x8*>(sb);          // mt0 hi
      const f16x8 b01 = *reinterpret_cast<const f16x8*>(sb + 1024);   // mt0 lo
      const f16x8 b10 = *reinterpret_cast<const f16x8*>(sb + 2048);   // mt1 hi
      const f16x8 b11 = *reinterpret_cast<const f16x8*>(sb + 3072);   // mt1 lo
      c0h = __builtin_amdgcn_mfma_f32_16x16x32_f16(A.v, b00, c0h, 0, 0, 0);
      c0l = __builtin_amdgcn_mfma_f32_16x16x32_f16(A.v, b01, c0l, 0, 0, 0);
      c1h = __builtin_amdgcn_mfma_f32_16x16x32_f16(A.v, b10, c1h, 0, 0, 0);
      c1l = __builtin_amdgcn_mfma_f32_16x16x32_f16(A.v, b11, c1l, 0, 0, 0);
    }
#pragma unroll
    for (int r = 0; r < 4; ++r) {
      const int row = (kg << 2) + r;
      scratch[wv][(row << 5) + cc]      = fmaf(c0l[r], INV4096, c0h[r]);
      scratch[wv][(row << 5) + cc + 16] = fmaf(c1l[r], INV4096, c1h[r]);
    }
    __syncthreads();                       // #2: partials ready

    // ---- K-reduce + state update for the 2 owned (b, m) ----
    const int o1 = (bl1 << 5) + ml_;
    const int o2 = (bl2 << 5) + ml_;
    const float rec1 =
        scratch[0][o1] + scratch[1][o1] + scratch[2][o1] + scratch[3][o1];
    const float rec2 =
        scratch[0][o2] + scratch[1][o2] + scratch[2][o2] + scratch[3][o2];

    syn1 = ALPHA_ * syn1 + h1 + rec1;
    mem1 = BETA_ * mem1 + syn1;
    const bool sp1 = (mem1 - THR_) > 0.f;
    spv1 = sp1 ? 1.f : 0.f;
    mem1 = sp1 ? 0.f : mem1;

    syn2 = ALPHA_ * syn2 + h2 + rec2;
    mem2 = BETA_ * mem2 + syn2;
    const bool sp2 = (mem2 - THR_) > 0.f;
    spv2 = sp2 ? 1.f : 0.f;
    mem2 = sp2 ? 0.f : mem2;

    // ---- publish spikes (tag t+1): WG's 16 words = 2 exclusive lines ----
    const unsigned long long ball1 = __ballot(sp1);
    const unsigned long long ball2 = __ballot(sp2);
    if (ml_ == 0) {                        // lanes 0 and 32 of each wave
      const unsigned sh = lane & 32;
      const unsigned long long tag = ((unsigned long long)(unsigned)(t + 1)) << 32;
      unsigned long long* nb = masks + (size_t)((t + 1) & 1) * 2048 + (size_t)mg * 64;
      __hip_atomic_store(nb + b1, tag | (unsigned)(ball1 >> sh),
                         __ATOMIC_RELAXED, __HIP_MEMORY_SCOPE_AGENT);
      __hip_atomic_store(nb + b2, tag | (unsigned)(ball2 >> sh),
                         __ATOMIC_RELAXED, __HIP_MEMORY_SCOPE_AGENT);
    }

    // ---- stream outputs (r9 placement: loop end, after publish) ----
    spk_rec[i1] = spv1; mem_rec[i1] = mem1; syn_rec[i1] = syn1;
    spk_rec[i2] = spv2; mem_rec[i2] = mem2; syn_rec[i2] = syn2;
  }

  mem_fin[b1 * N_ + m] = mem1; syn_fin[b1 * N_ + m] = syn1; spk_fin[b1 * N_ + m] = spv1;
  mem_fin[b2 * N_ + m] = mem2; syn_fin[b2 * N_ + m] = syn2; spk_fin[b2 * N_ + m] = spv2;
}

// ============================== launcher =====================================
extern "C" void kernel_launch(void* const* d_in, const int* in_sizes, int n_in,
                              void* d_out, int out_size, void* d_ws, size_t ws_size,
                              hipStream_t stream) {
  const float* X  = (const float*)d_in[0];
  const float* W  = (const float*)d_in[1];
  const float* Rw = (const float*)d_in[2];

  float* out = (float*)d_out;
  const size_t BTN = (size_t)B_ * T_ * N_;
  const size_t BN  = (size_t)B_ * N_;
  float* spk_rec = out;
  float* mem_fin = out + BTN;
  float* syn_fin = mem_fin + BN;
  float* spk_fin = syn_fin + BN;
  float* mem_rec = spk_fin + BN;
  float* syn_rec = mem_rec + BTN;  // doubles as the H buffer

  // W-fragment scratch in mem_rec (hgemm2 finishes before step overwrites it)
  unsigned char* Wfrag = (unsigned char*)mem_rec;

  unsigned long long* masks = (unsigned long long*)d_ws;
  hipMemsetAsync(d_ws, 0, (size_t)2 * 2048 * sizeof(unsigned long long), stream);

  dsrnn_wsplit<<<dim3(256), dim3(256), 0, stream>>>(W, Wfrag);
  dsrnn_hgemm2<<<dim3(2048), dim3(256), 0, stream>>>(X, Wfrag, syn_rec);

  (void)hipFuncSetAttribute((const void*)dsrnn_step13,
                            hipFuncAttributeMaxDynamicSharedMemorySize, 131072);
  void* args[] = {(void*)&Rw,      (void*)&spk_rec, (void*)&mem_rec,
                  (void*)&syn_rec, (void*)&mem_fin, (void*)&syn_fin,
                  (void*)&spk_fin, (void*)&masks};
  hipLaunchCooperativeKernel((void*)dsrnn_step13, dim3(128), dim3(256), args,
                             131072, stream);
}

// Round 14
// 742.771 us; speedup vs baseline: 1.2498x; 1.2498x over previous
//
#include <hip/hip_runtime.h>

typedef __attribute__((ext_vector_type(8))) _Float16 f16x8;
typedef __attribute__((ext_vector_type(4))) float f32x4;

static constexpr int   B_  = 64;
static constexpr int   T_  = 256;
static constexpr int   D_  = 512;
static constexpr int   N_  = 1024;
static constexpr float ALPHA_ = 0.9f;
static constexpr float BETA_  = 0.85f;
static constexpr float THR_   = 0.1f;
static constexpr float INV4096 = 1.0f / 4096.0f;

// ========== Kernel 0: pre-split + pre-fragment W into MFMA B-blocks ==========
__global__ __launch_bounds__(256) void dsrnn_wsplit(const float* __restrict__ W,
                                                    unsigned char* __restrict__ Wfrag) {
  const int u    = blockIdx.x * 256 + threadIdx.x;   // 0..65535
  const int lane = u & 63;
  const int bi   = u >> 6;        // 0..1023 = cf*16 + ch
  const int cf   = bi >> 4;
  const int chk  = bi & 15;
  const int kg   = lane >> 4;
  const int cc   = lane & 15;
  const int n    = cf * 16 + cc;
  const int k0   = chk * 32 + kg * 8;
  f16x8 vh, vl;
#pragma unroll
  for (int j = 0; j < 8; ++j) {
    const float v = W[(size_t)(k0 + j) * N_ + n];
    const _Float16 h = (_Float16)v;
    vh[j] = h;
    vl[j] = (_Float16)((v - (float)h) * 4096.0f);
  }
  unsigned char* dst = Wfrag + (size_t)bi * 2048 + lane * 16;
  *reinterpret_cast<f16x8*>(dst)        = vh;
  *reinterpret_cast<f16x8*>(dst + 1024) = vl;
}

// ================= Kernel 1: H = X @ W via MFMA (fp16 3-product) =============
__global__ __launch_bounds__(256) void dsrnn_hgemm2(const float* __restrict__ X,
                                                    const unsigned char* __restrict__ Wfrag,
                                                    float* __restrict__ H) {
  __shared__ __align__(16) _Float16 Xa_hi[64][40];
  __shared__ __align__(16) _Float16 Xa_lo[64][40];
  const int tid  = threadIdx.x;
  const int rb   = blockIdx.x >> 3;
  const int nb   = (blockIdx.x & 7) << 7;
  const int r0   = rb << 6;
  const int wv   = tid >> 6;
  const int lane = tid & 63;
  const int kg   = lane >> 4;
  const int cc   = lane & 15;

  f32x4 ah[4][2], am[4][2];
#pragma unroll
  for (int i = 0; i < 4; ++i)
#pragma unroll
    for (int j = 0; j < 2; ++j) {
      ah[i][j] = (f32x4){0.f, 0.f, 0.f, 0.f};
      am[i][j] = (f32x4){0.f, 0.f, 0.f, 0.f};
    }

  const int srow = tid >> 2;
  const int skq  = (tid & 3) << 3;

  for (int kc = 0; kc < 16; ++kc) {
    {
      const float* xp = X + (size_t)(r0 + srow) * D_ + kc * 32 + skq;
      const float4 v0 = *reinterpret_cast<const float4*>(xp);
      const float4 v1 = *reinterpret_cast<const float4*>(xp + 4);
      const float vv[8] = {v0.x, v0.y, v0.z, v0.w, v1.x, v1.y, v1.z, v1.w};
      f16x8 xh, xl;
#pragma unroll
      for (int j = 0; j < 8; ++j) {
        const _Float16 h = (_Float16)vv[j];
        xh[j] = h;
        xl[j] = (_Float16)((vv[j] - (float)h) * 4096.0f);
      }
      *reinterpret_cast<f16x8*>(&Xa_hi[srow][skq]) = xh;
      *reinterpret_cast<f16x8*>(&Xa_lo[srow][skq]) = xl;
    }
    __syncthreads();

    f16x8 Bh[2], Bl[2];
#pragma unroll
    for (int cfi = 0; cfi < 2; ++cfi) {
      const unsigned char* bp =
          Wfrag + (size_t)((((nb >> 4) + (wv << 1) + cfi) * 16 + kc) * 2048) + lane * 16;
      Bh[cfi] = *reinterpret_cast<const f16x8*>(bp);
      Bl[cfi] = *reinterpret_cast<const f16x8*>(bp + 1024);
    }

#pragma unroll
    for (int rf = 0; rf < 4; ++rf) {
      const f16x8 Ah = *reinterpret_cast<const f16x8*>(&Xa_hi[rf * 16 + cc][kg * 8]);
      const f16x8 Al = *reinterpret_cast<const f16x8*>(&Xa_lo[rf * 16 + cc][kg * 8]);
#pragma unroll
      for (int cfi = 0; cfi < 2; ++cfi) {
        ah[rf][cfi] = __builtin_amdgcn_mfma_f32_16x16x32_f16(Ah, Bh[cfi], ah[rf][cfi], 0, 0, 0);
        am[rf][cfi] = __builtin_amdgcn_mfma_f32_16x16x32_f16(Ah, Bl[cfi], am[rf][cfi], 0, 0, 0);
        am[rf][cfi] = __builtin_amdgcn_mfma_f32_16x16x32_f16(Al, Bh[cfi], am[rf][cfi], 0, 0, 0);
      }
    }
    __syncthreads();
  }

#pragma unroll
  for (int rf = 0; rf < 4; ++rf)
#pragma unroll
    for (int cfi = 0; cfi < 2; ++cfi) {
      const int col = nb + wv * 32 + cfi * 16 + cc;
#pragma unroll
      for (int rr = 0; rr < 4; ++rr) {
        const int row = r0 + rf * 16 + kg * 4 + rr;
        H[(size_t)row * N_ + col] = fmaf(am[rf][cfi][rr], INV4096, ah[rf][cfi][rr]);
      }
    }
}

// ====== Kernel 2: persistent recurrence via MFMA (fp16 hi + scaled-lo) =======
// BYTE-EXACT r9 structure (measured 660 us): [b][mg] masks layout (coalesced
// spin reads), whole-WG throttled PARALLEL spin (s_sleep(1)), LDS mask stage,
// 2 barriers/step, publish immediately after state update, outputs streamed
// at loop end. Every attempted variation regressed (r8/r10-r13 ledger); this
// is the measured local optimum of the sync microstructure.
__global__ __launch_bounds__(256, 1) void dsrnn_step14(
    const float* __restrict__ Rw,
    float* __restrict__ spk_rec,
    float* __restrict__ mem_rec,
    float* __restrict__ syn_rec,   // pre-filled with H, overwritten with syn
    float* __restrict__ mem_fin,
    float* __restrict__ syn_fin,
    float* __restrict__ spk_fin,
    unsigned long long* masks)     // [2 parity][64 b][32 mg]
{
  extern __shared__ unsigned char RsB[];   // 128 KB fragment blocks
  __shared__ unsigned smaskU[16][33];      // padded
  __shared__ float scratch[4][512];        // per-wave C partials [wv][b*32+m]

  const int tid  = threadIdx.x;
  const int bq   = blockIdx.x >> 5;
  const int mg   = blockIdx.x & 31;
  const int wv   = tid >> 6;
  const int lane = tid & 63;
  const int kg   = lane >> 4;
  const int cc   = lane & 15;

  // ---- one-time preload: R[:, mg*32..+32) -> fp16 hi / scaled-lo blocks ----
  for (int k = 0; k < 128; ++k) {
    const int e  = (k << 8) + tid;
    const int n  = e >> 5;
    const int ml = e & 31;
    const float v = Rw[(size_t)n * N_ + (mg << 5) + ml];
    const _Float16 hi = (_Float16)v;
    const float hif = (float)hi;
    const _Float16 lo = (_Float16)((v - hif) * 4096.0f);
    const int s   = n >> 5;
    const int kin = n & 31;
    const int ln  = ((kin >> 3) << 4) + (ml & 15);
    const int mt  = ml >> 4;
    const int off = ((((s << 1) + mt) << 1) << 10) + (ln << 4) + ((kin & 7) << 1);
    *(_Float16*)(RsB + off)        = hi;
    *(_Float16*)(RsB + off + 1024) = lo;
  }

  const int bl1 = tid >> 5;                // 0..7
  const int bl2 = bl1 + 8;
  const int ml_ = tid & 31;
  const int b1  = (bq << 4) + bl1;
  const int b2  = (bq << 4) + bl2;
  const int m   = (mg << 5) + ml_;

  float mem1 = 0.f, syn1 = 0.f, spv1 = 0.f;
  float mem2 = 0.f, syn2 = 0.f, spv2 = 0.f;

  __syncthreads();                         // preload visible to all

  for (int t = 0; t < T_; ++t) {
    const size_t i1 = ((size_t)b1 * T_ + t) * N_ + m;
    const size_t i2 = ((size_t)b2 * T_ + t) * N_ + m;
    const float h1 = syn_rec[i1];          // issue early, consumed post-GEMM
    const float h2 = syn_rec[i2];

    // ---- PARALLEL throttled spin for the two owned mask words (tag == t) ----
    {
      unsigned long long* base = masks + (size_t)(t & 1) * 2048;
      unsigned long long* p1 = base + (size_t)b1 * 32 + ml_;
      unsigned long long* p2 = base + (size_t)b2 * 32 + ml_;
      unsigned long long w1 =
          __hip_atomic_load(p1, __ATOMIC_RELAXED, __HIP_MEMORY_SCOPE_AGENT);
      unsigned long long w2 =
          __hip_atomic_load(p2, __ATOMIC_RELAXED, __HIP_MEMORY_SCOPE_AGENT);
      int g = 0;
      while ((((unsigned)(w1 >> 32) != (unsigned)t) |
              ((unsigned)(w2 >> 32) != (unsigned)t)) && ++g < (1 << 20)) {
        __builtin_amdgcn_s_sleep(1);
        w1 = __hip_atomic_load(p1, __ATOMIC_RELAXED, __HIP_MEMORY_SCOPE_AGENT);
        w2 = __hip_atomic_load(p2, __ATOMIC_RELAXED, __HIP_MEMORY_SCOPE_AGENT);
      }
      smaskU[bl1][ml_] = (unsigned)w1;
      smaskU[bl2][ml_] = (unsigned)w2;
    }
    __syncthreads();                       // #1: masks staged

    // ---- MFMA phase: wave's 8 K-steps; hi and lo into separate fp32 C ----
    f32x4 c0h = {0.f, 0.f, 0.f, 0.f};
    f32x4 c0l = {0.f, 0.f, 0.f, 0.f};
    f32x4 c1h = {0.f, 0.f, 0.f, 0.f};
    f32x4 c1l = {0.f, 0.f, 0.f, 0.f};
    const int shB = kg << 3;
#pragma unroll
    for (int ss = 0; ss < 8; ++ss) {
      const int s = (wv << 3) + ss;
      const unsigned bits8 = (smaskU[cc][s] >> shB) & 0xFFu;
      union { unsigned u[4]; f16x8 v; } A;
#pragma unroll
      for (int p = 0; p < 4; ++p) {
        const unsigned e0 = (bits8 >> (2 * p)) & 1u;
        const unsigned e1 = (bits8 >> (2 * p + 1)) & 1u;
        A.u[p] = e0 * 0x3C00u + e1 * 0x3C000000u;   // fp16 1.0 per slot
      }
      const unsigned char* sb = RsB + (s << 12) + (lane << 4);
      const f16x8 b00 = *reinterpret_cast<const f16x8*>(sb);          // mt0 hi
      const f16x8 b01 = *reinterpret_cast<const f16x8*>(sb + 1024);   // mt0 lo
      const f16x8 b10 = *reinterpret_cast<const f16x8*>(sb + 2048);   // mt1 hi
      const f16x8 b11 = *reinterpret_cast<const f16x8*>(sb + 3072);   // mt1 lo
      c0h = __builtin_amdgcn_mfma_f32_16x16x32_f16(A.v, b00, c0h, 0, 0, 0);
      c0l = __builtin_amdgcn_mfma_f32_16x16x32_f16(A.v, b01, c0l, 0, 0, 0);
      c1h = __builtin_amdgcn_mfma_f32_16x16x32_f16(A.v, b10, c1h, 0, 0, 0);
      c1l = __builtin_amdgcn_mfma_f32_16x16x32_f16(A.v, b11, c1l, 0, 0, 0);
    }
#pragma unroll
    for (int r = 0; r < 4; ++r) {
      const int row = (kg << 2) + r;
      scratch[wv][(row << 5) + cc]      = fmaf(c0l[r], INV4096, c0h[r]);
      scratch[wv][(row << 5) + cc + 16] = fmaf(c1l[r], INV4096, c1h[r]);
    }
    __syncthreads();                       // #2: partials ready

    // ---- K-reduce + state update for the 2 owned (b, m) ----
    const int o1 = (bl1 << 5) + ml_;
    const int o2 = (bl2 << 5) + ml_;
    const float rec1 =
        scratch[0][o1] + scratch[1][o1] + scratch[2][o1] + scratch[3][o1];
    const float rec2 =
        scratch[0][o2] + scratch[1][o2] + scratch[2][o2] + scratch[3][o2];

    syn1 = ALPHA_ * syn1 + h1 + rec1;
    mem1 = BETA_ * mem1 + syn1;
    const bool sp1 = (mem1 - THR_) > 0.f;
    spv1 = sp1 ? 1.f : 0.f;
    mem1 = sp1 ? 0.f : mem1;

    syn2 = ALPHA_ * syn2 + h2 + rec2;
    mem2 = BETA_ * mem2 + syn2;
    const bool sp2 = (mem2 - THR_) > 0.f;
    spv2 = sp2 ? 1.f : 0.f;
    mem2 = sp2 ? 0.f : mem2;

    // ---- publish spikes (tag t+1) immediately ----
    const unsigned long long ball1 = __ballot(sp1);
    const unsigned long long ball2 = __ballot(sp2);
    if (ml_ == 0) {                        // lanes 0 and 32 of each wave
      const unsigned sh = lane & 32;
      const unsigned long long tag = ((unsigned long long)(unsigned)(t + 1)) << 32;
      unsigned long long* nb = masks + (size_t)((t + 1) & 1) * 2048;
      __hip_atomic_store(nb + (size_t)b1 * 32 + mg,
                         tag | (unsigned)(ball1 >> sh),
                         __ATOMIC_RELAXED, __HIP_MEMORY_SCOPE_AGENT);
      __hip_atomic_store(nb + (size_t)b2 * 32 + mg,
                         tag | (unsigned)(ball2 >> sh),
                         __ATOMIC_RELAXED, __HIP_MEMORY_SCOPE_AGENT);
    }

    // ---- stream outputs (loop end, after publish) ----
    spk_rec[i1] = spv1; mem_rec[i1] = mem1; syn_rec[i1] = syn1;
    spk_rec[i2] = spv2; mem_rec[i2] = mem2; syn_rec[i2] = syn2;
  }

  mem_fin[b1 * N_ + m] = mem1; syn_fin[b1 * N_ + m] = syn1; spk_fin[b1 * N_ + m] = spv1;
  mem_fin[b2 * N_ + m] = mem2; syn_fin[b2 * N_ + m] = syn2; spk_fin[b2 * N_ + m] = spv2;
}

// ============================== launcher =====================================
extern "C" void kernel_launch(void* const* d_in, const int* in_sizes, int n_in,
                              void* d_out, int out_size, void* d_ws, size_t ws_size,
                              hipStream_t stream) {
  const float* X  = (const float*)d_in[0];
  const float* W  = (const float*)d_in[1];
  const float* Rw = (const float*)d_in[2];

  float* out = (float*)d_out;
  const size_t BTN = (size_t)B_ * T_ * N_;
  const size_t BN  = (size_t)B_ * N_;
  float* spk_rec = out;
  float* mem_fin = out + BTN;
  float* syn_fin = mem_fin + BN;
  float* spk_fin = syn_fin + BN;
  float* mem_rec = spk_fin + BN;
  float* syn_rec = mem_rec + BTN;  // doubles as the H buffer

  // W-fragment scratch in mem_rec (hgemm2 finishes before step overwrites it)
  unsigned char* Wfrag = (unsigned char*)mem_rec;

  unsigned long long* masks = (unsigned long long*)d_ws;
  hipMemsetAsync(d_ws, 0, (size_t)2 * 2048 * sizeof(unsigned long long), stream);

  dsrnn_wsplit<<<dim3(256), dim3(256), 0, stream>>>(W, Wfrag);
  dsrnn_hgemm2<<<dim3(2048), dim3(256), 0, stream>>>(X, Wfrag, syn_rec);

  (void)hipFuncSetAttribute((const void*)dsrnn_step14,
                            hipFuncAttributeMaxDynamicSharedMemorySize, 131072);
  void* args[] = {(void*)&Rw,      (void*)&spk_rec, (void*)&mem_rec,
                  (void*)&syn_rec, (void*)&mem_fin, (void*)&syn_fin,
                  (void*)&spk_fin, (void*)&masks};
  hipLaunchCooperativeKernel((void*)dsrnn_step14, dim3(128), dim3(256), args,
                             131072, stream);
}